// Round 3
// baseline (198.924 us; speedup 1.0000x reference)
//
#include <hip/hip_runtime.h>

// BlockResMLP mixer, fused single kernel — swapped-MFMA version, K=32-only.
// 16384 rows x 1024 cols fp32. Two layers of per-block MLP(32->64 ELU ->32)+residual,
// 32x32 cross-block transpose between layers (gap=1 then gap=32).
//
// GEMM1 computed SWAPPED (hT = mfma(A=W1^T-frag, B=x^T-frag)) so each lane ends up
// holding h[16c+4q+r][t] — reg r is feature 16c+4q+r. GEMM2 (yT = W2^T @ hT) chains
// with ZERO data movement: the K=32 B-fragment over chunk-pair e is the register
// CONCATENATION {av[2e], av[2e+1]} under the k-relabeling
//   feature(k=8q+j) = 32e + 16*(j>=4) + 4q + (j&3),
// and the W2 pack permutes features identically. Only mfma_f32_16x16x32_bf16 is used
// (the exact opcode the measured round-0 baseline ran). Biases fold into MFMA C.
// Inter-layer transpose via one 32KB bf16 tile [colblk][row][k] with XOR swizzle
// (bits 2..5), giving vector ds_read_b64 gathers and 4-way-max writer conflicts.

typedef unsigned short u16t;
typedef __bf16 bf16x8 __attribute__((ext_vector_type(8)));
typedef __bf16 bf16x4 __attribute__((ext_vector_type(4)));
typedef float f32x4 __attribute__((ext_vector_type(4)));

__device__ __forceinline__ u16t f2b(float f) {           // fp32 -> bf16 RNE (pack kernel)
  union { float f; unsigned u; } v; v.f = f;
  unsigned r = v.u + 0x7FFFu + ((v.u >> 16) & 1u);
  return (u16t)(r >> 16);
}
__device__ __forceinline__ float b2f(u16t h) {
  union { unsigned u; float f; } v; v.u = ((unsigned)h) << 16;
  return v.f;
}
__device__ __forceinline__ u16t f2b_hw(float f) {        // HW v_cvt (RNE) path
  union { __bf16 h; u16t u; } v; v.h = (__bf16)f;
  return v.u;
}

// Tile swizzle: XOR bits 2..5 with (bits 6..9 ^ bits 10..13). Keeps 8B groups
// contiguous+aligned (vector reads OK) and spreads the writer's 512-u16-strided
// scalar stores across banks (4-way max conflict).
__device__ __forceinline__ int swz(int idx) {
  return idx ^ ((((idx >> 6) ^ (idx >> 10)) & 15) << 2);
}

// ---------------- weight pack: fp32 -> bf16 MFMA fragment order ----------------
// pW1[L][n][c][lane][j]  : W1[n][k=q*8+j][c*16+t]                       (A-frag, K=32)
// pW2[L][n][f][lane][j]  : f = e*2+c2;
//     j<4 : W2[n][32e      + 4q + j    ][16c2+t]
//     j>=4: W2[n][32e + 16 + 4q + (j-4)][16c2+t]                        (A-frag, K=32, paired chunks)
__global__ __launch_bounds__(256) void pack_weights(
    const float* __restrict__ W1a, const float* __restrict__ W2a,
    const float* __restrict__ W1b, const float* __restrict__ W2b,
    u16t* __restrict__ pW1, u16t* __restrict__ pW2) {
  int tidg = blockIdx.x * 256 + threadIdx.x;   // 0..32767
  int tensor = tidg >> 14;                     // 0 = W1, 1 = W2
  int r  = tidg & 16383;
  int L  = r >> 13;
  int r2 = r & 8191;
  int n    = r2 >> 8;
  int f    = (r2 >> 6) & 3;
  int lane = r2 & 63;
  int q = lane >> 4, t = lane & 15;

  union { u16t us[8]; uint4 v; } w;
  if (tensor == 0) {
    const float* src = L ? W1b : W1a;
#pragma unroll
    for (int j = 0; j < 8; j++)
      w.us[j] = f2b(src[n * 2048 + (q * 8 + j) * 64 + f * 16 + t]);
    *(uint4*)(pW1 + (size_t)((((L * 32 + n) * 4 + f) * 64 + lane) * 8)) = w.v;
  } else {
    const float* src = L ? W2b : W2a;
    int e = f >> 1, c2 = f & 1;
#pragma unroll
    for (int j = 0; j < 8; j++) {
      int feat = 32 * e + (j >= 4 ? 16 : 0) + 4 * q + (j & 3);
      w.us[j] = f2b(src[n * 2048 + feat * 32 + 16 * c2 + t]);
    }
    *(uint4*)(pW2 + (size_t)((((L * 32 + n) * 4 + f) * 64 + lane) * 8)) = w.v;
  }
}

// ---------------- per-layer compute (8 blocks per wave) ----------------
// afr[u]: x-frag, lane (q,t) holds x[t][8q+j] of block n0+u (A or B role identically).
// Writes y[t][32n + cc] (cc = 16c2+4q+r) to tile at logical idx = cc*512 + t*32 + n.
template <int L>
__device__ __forceinline__ void compute_layer(
    const bf16x8* __restrict__ afr, u16t* __restrict__ tile,
    const u16t* __restrict__ pW1, const u16t* __restrict__ pW2,
    const float* __restrict__ b1, const float* __restrict__ b2,
    int n0, int lane, int q, int t, const bf16x8* __restrict__ ifr) {
#pragma unroll
  for (int u = 0; u < 8; u++) {
    const int n = n0 + u;
    const int wbase = ((L * 32 + n) * 4) * 512 + lane * 8;

    bf16x8 w1f[4], w2f[4];
    f32x4 b1f[4], b2f2[2];
#pragma unroll
    for (int c = 0; c < 4; c++) {
      w1f[c] = *(const bf16x8*)(pW1 + wbase + c * 512);
      w2f[c] = *(const bf16x8*)(pW2 + wbase + c * 512);
      b1f[c] = *(const f32x4*)(b1 + n * 64 + c * 16 + q * 4);
    }
    b2f2[0] = *(const f32x4*)(b2 + n * 32 + q * 4);
    b2f2[1] = *(const f32x4*)(b2 + n * 32 + 16 + q * 4);

    // GEMM1 swapped: D = W1^T_chunk @ x^T (+ b1 via C). Lane reg r = h[16c+4q+r][t].
    f32x4 hacc[4];
#pragma unroll
    for (int c = 0; c < 4; c++)
      hacc[c] = __builtin_amdgcn_mfma_f32_16x16x32_bf16(w1f[c], afr[u], b1f[c], 0, 0, 0);

    // ELU + bf16 cvt, in-register. av[c][r] = hT feature 16c+4q+r (col t).
    bf16x4 av[4];
#pragma unroll
    for (int c = 0; c < 4; c++) {
#pragma unroll
      for (int r = 0; r < 4; r++) {
        float v = hacc[c][r];
        v = fmaxf(v, 0.f) + fminf(__expf(v) - 1.f, 0.f);   // ELU
        av[c][r] = (__bf16)v;
      }
    }
    // K=32 B-frags for GEMM2: concat chunk pair (2e, 2e+1) per the feature(k) relabel.
    bf16x8 bfrag[2];
#pragma unroll
    for (int e = 0; e < 2; e++)
      bfrag[e] = __builtin_shufflevector(av[2 * e], av[2 * e + 1], 0, 1, 2, 3, 4, 5, 6, 7);

    // GEMM2 swapped: yT = W2^T @ hT, residual via identity-A MFMA, b2 via C.
#pragma unroll
    for (int c2 = 0; c2 < 2; c2++) {
      f32x4 acc = __builtin_amdgcn_mfma_f32_16x16x32_bf16(ifr[c2], afr[u], b2f2[c2], 0, 0, 0);
#pragma unroll
      for (int e = 0; e < 2; e++)
        acc = __builtin_amdgcn_mfma_f32_16x16x32_bf16(w2f[e * 2 + c2], bfrag[e], acc, 0, 0, 0);
#pragma unroll
      for (int r = 0; r < 4; r++) {
        int cc  = c2 * 16 + q * 4 + r;          // out col within block
        int idx = cc * 512 + t * 32 + n;        // [colblk][row][k=n]
        tile[swz(idx)] = f2b_hw(acc[r]);
      }
    }
  }
}

__global__ __launch_bounds__(256, 4) void mixer_kernel(
    const float* __restrict__ x,
    const float* __restrict__ b1a, const float* __restrict__ b2a,
    const float* __restrict__ b1b, const float* __restrict__ b2b,
    const u16t* __restrict__ pW1, const u16t* __restrict__ pW2,
    float* __restrict__ out) {
  __shared__ u16t tile[16384];                  // 32 KB: [colblk 0..31][row 0..15][k 0..31]

  const int tid  = threadIdx.x;
  const int wave = tid >> 6, lane = tid & 63;
  const int q = lane >> 4, t = lane & 15;
  const int r0 = blockIdx.x * 16;
  const int n0 = wave * 8;

  // identity A-frags for the swapped residual MFMA: A[m=t][k=8q+j] = (8q+j == 16c2+t)
  bf16x8 ifr[2];
#pragma unroll
  for (int c2 = 0; c2 < 2; c2++) {
    union { u16t us[8]; bf16x8 v; } w;
#pragma unroll
    for (int j = 0; j < 8; j++)
      w.us[j] = ((q * 8 + j) == (c2 * 16 + t)) ? (u16t)0x3F80 : (u16t)0;
    ifr[c2] = w.v;
  }

  // ---- layer 1 input frags straight from global ----
  bf16x8 afr[8];
#pragma unroll
  for (int u = 0; u < 8; u++) {
    const float* gp = x + (size_t)(r0 + t) * 1024 + (n0 + u) * 32 + q * 8;
    float4 v0 = *(const float4*)gp;
    float4 v1 = *(const float4*)(gp + 4);
    union { __bf16 h[8]; bf16x8 v; } a;
    a.h[0] = (__bf16)v0.x; a.h[1] = (__bf16)v0.y; a.h[2] = (__bf16)v0.z; a.h[3] = (__bf16)v0.w;
    a.h[4] = (__bf16)v1.x; a.h[5] = (__bf16)v1.y; a.h[6] = (__bf16)v1.z; a.h[7] = (__bf16)v1.w;
    afr[u] = a.v;
  }

  compute_layer<0>(afr, tile, pW1, pW2, b1a, b2a, n0, lane, q, t, ifr);
  __syncthreads();

  // ---- layer 2 gather: z_n2[t][8q+j] = y1[t][(8q+j)*32 + n2] -> two ds_read_b64 per u ----
#pragma unroll
  for (int u = 0; u < 8; u++) {
    const int n2 = n0 + u;
    int idx = n2 * 512 + t * 32 + q * 8;
    union { ushort4 h[2]; bf16x8 v; } a;
    a.h[0] = *(const ushort4*)&tile[swz(idx)];
    a.h[1] = *(const ushort4*)&tile[swz(idx + 4)];
    afr[u] = a.v;
  }
  __syncthreads();                              // gathers done before tile is overwritten

  compute_layer<1>(afr, tile, pW1, pW2, b1b, b2b, n0, lane, q, t, ifr);
  __syncthreads();

  // ---- output: out[m][cc*32+n2] = y2[m][32*n2+cc]; tile layout makes this 4-contig ----
#pragma unroll
  for (int i = 0; i < 16; i++) {
    int c  = tid >> 3;
    int n2 = (tid & 7) * 4;
    int idx = c * 512 + i * 32 + n2;
    ushort4 hv = *(const ushort4*)&tile[swz(idx)];
    float4 o;
    o.x = b2f(hv.x); o.y = b2f(hv.y); o.z = b2f(hv.z); o.w = b2f(hv.w);
    *(float4*)(out + (size_t)(r0 + i) * 1024 + tid * 4) = o;
  }
}

extern "C" void kernel_launch(void* const* d_in, const int* in_sizes, int n_in,
                              void* d_out, int out_size, void* d_ws, size_t ws_size,
                              hipStream_t stream) {
  const float* x   = (const float*)d_in[0];
  const float* W1a = (const float*)d_in[1];
  const float* b1a = (const float*)d_in[2];
  const float* W2a = (const float*)d_in[3];
  const float* b2a = (const float*)d_in[4];
  const float* W1b = (const float*)d_in[5];
  const float* b1b = (const float*)d_in[6];
  const float* W2b = (const float*)d_in[7];
  const float* b2b = (const float*)d_in[8];
  float* out = (float*)d_out;

  u16t* pW1 = (u16t*)d_ws;
  u16t* pW2 = pW1 + 131072;   // 256 KB each, 512 KB total in d_ws

  const int rows = in_sizes[0] / 1024;

  pack_weights<<<128, 256, 0, stream>>>(W1a, W2a, W1b, W2b, pW1, pW2);
  mixer_kernel<<<rows / 16, 256, 0, stream>>>(x, b1a, b2a, b1b, b2b, pW1, pW2, out);
}

// Round 4
// 182.583 us; speedup vs baseline: 1.0895x; 1.0895x over previous
//
#include <hip/hip_runtime.h>

// BlockResMLP mixer, fused single kernel — swapped-MFMA version, K=32-only.
// 16384 rows x 1024 cols fp32. Two layers of per-block MLP(32->64 ELU ->32)+residual,
// 32x32 cross-block transpose between layers (gap=1 then gap=32).
//
// GEMM1 computed SWAPPED (hT = mfma(A=W1^T-frag, B=x^T-frag)) so each lane ends up
// holding h[16c+4q+r][t] — reg r is feature 16c+4q+r. GEMM2 (yT = W2^T @ hT) chains
// with ZERO data movement: the K=32 B-fragment over chunk-pair e is the register
// CONCATENATION {av[2e], av[2e+1]} under the k-relabeling
//   feature(k=8q+j) = 32e + 16*(j>=4) + 4q + (j&3),
// and the W2 pack permutes features identically. Only mfma_f32_16x16x32_bf16 is used.
// Biases fold into MFMA C. Inter-layer transpose via one 32KB bf16 tile
// [colblk][row][k] with XOR swizzle (bits 2..5): vector ds_read_b64 gathers,
// 4-way-max writer conflicts.
//
// NOTE (round-3 post-mortem): __launch_bounds__(256, 4) clamped VGPRs to 64 ->
// ~80 MB/dispatch scratch spill, MfmaUtil 0.085%. Plain (256) restores the
// spill-free allocation (~88-128 VGPR). Do NOT re-add a waves-per-EU hint here.

typedef unsigned short u16t;
typedef __bf16 bf16x8 __attribute__((ext_vector_type(8)));
typedef __bf16 bf16x4 __attribute__((ext_vector_type(4)));
typedef float f32x4 __attribute__((ext_vector_type(4)));

__device__ __forceinline__ u16t f2b(float f) {           // fp32 -> bf16 RNE (pack kernel)
  union { float f; unsigned u; } v; v.f = f;
  unsigned r = v.u + 0x7FFFu + ((v.u >> 16) & 1u);
  return (u16t)(r >> 16);
}
__device__ __forceinline__ float b2f(u16t h) {
  union { unsigned u; float f; } v; v.u = ((unsigned)h) << 16;
  return v.f;
}
__device__ __forceinline__ u16t f2b_hw(float f) {        // HW v_cvt (RNE) path
  union { __bf16 h; u16t u; } v; v.h = (__bf16)f;
  return v.u;
}

// Tile swizzle: XOR bits 2..5 with (bits 6..9 ^ bits 10..13). Keeps 8B groups
// contiguous+aligned (vector reads OK) and spreads the writer's 512-u16-strided
// scalar stores across banks (4-way max conflict).
__device__ __forceinline__ int swz(int idx) {
  return idx ^ ((((idx >> 6) ^ (idx >> 10)) & 15) << 2);
}

// ---------------- weight pack: fp32 -> bf16 MFMA fragment order ----------------
// pW1[L][n][c][lane][j]  : W1[n][k=q*8+j][c*16+t]                       (A-frag, K=32)
// pW2[L][n][f][lane][j]  : f = e*2+c2;
//     j<4 : W2[n][32e      + 4q + j    ][16c2+t]
//     j>=4: W2[n][32e + 16 + 4q + (j-4)][16c2+t]                        (A-frag, K=32, paired chunks)
__global__ __launch_bounds__(256) void pack_weights(
    const float* __restrict__ W1a, const float* __restrict__ W2a,
    const float* __restrict__ W1b, const float* __restrict__ W2b,
    u16t* __restrict__ pW1, u16t* __restrict__ pW2) {
  int tidg = blockIdx.x * 256 + threadIdx.x;   // 0..32767
  int tensor = tidg >> 14;                     // 0 = W1, 1 = W2
  int r  = tidg & 16383;
  int L  = r >> 13;
  int r2 = r & 8191;
  int n    = r2 >> 8;
  int f    = (r2 >> 6) & 3;
  int lane = r2 & 63;
  int q = lane >> 4, t = lane & 15;

  union { u16t us[8]; uint4 v; } w;
  if (tensor == 0) {
    const float* src = L ? W1b : W1a;
#pragma unroll
    for (int j = 0; j < 8; j++)
      w.us[j] = f2b(src[n * 2048 + (q * 8 + j) * 64 + f * 16 + t]);
    *(uint4*)(pW1 + (size_t)((((L * 32 + n) * 4 + f) * 64 + lane) * 8)) = w.v;
  } else {
    const float* src = L ? W2b : W2a;
    int e = f >> 1, c2 = f & 1;
#pragma unroll
    for (int j = 0; j < 8; j++) {
      int feat = 32 * e + (j >= 4 ? 16 : 0) + 4 * q + (j & 3);
      w.us[j] = f2b(src[n * 2048 + feat * 32 + 16 * c2 + t]);
    }
    *(uint4*)(pW2 + (size_t)((((L * 32 + n) * 4 + f) * 64 + lane) * 8)) = w.v;
  }
}

// ---------------- per-layer compute (8 blocks per wave) ----------------
// afr[u]: x-frag, lane (q,t) holds x[t][8q+j] of block n0+u (A or B role identically).
// Writes y[t][32n + cc] (cc = 16c2+4q+r) to tile at logical idx = cc*512 + t*32 + n.
template <int L>
__device__ __forceinline__ void compute_layer(
    const bf16x8* __restrict__ afr, u16t* __restrict__ tile,
    const u16t* __restrict__ pW1, const u16t* __restrict__ pW2,
    const float* __restrict__ b1, const float* __restrict__ b2,
    int n0, int lane, int q, int t, const bf16x8* __restrict__ ifr) {
#pragma unroll
  for (int u = 0; u < 8; u++) {
    const int n = n0 + u;
    const int wbase = ((L * 32 + n) * 4) * 512 + lane * 8;

    bf16x8 w1f[4], w2f[4];
    f32x4 b1f[4], b2f2[2];
#pragma unroll
    for (int c = 0; c < 4; c++) {
      w1f[c] = *(const bf16x8*)(pW1 + wbase + c * 512);
      w2f[c] = *(const bf16x8*)(pW2 + wbase + c * 512);
      b1f[c] = *(const f32x4*)(b1 + n * 64 + c * 16 + q * 4);
    }
    b2f2[0] = *(const f32x4*)(b2 + n * 32 + q * 4);
    b2f2[1] = *(const f32x4*)(b2 + n * 32 + 16 + q * 4);

    // GEMM1 swapped: D = W1^T_chunk @ x^T (+ b1 via C). Lane reg r = h[16c+4q+r][t].
    f32x4 hacc[4];
#pragma unroll
    for (int c = 0; c < 4; c++)
      hacc[c] = __builtin_amdgcn_mfma_f32_16x16x32_bf16(w1f[c], afr[u], b1f[c], 0, 0, 0);

    // ELU + bf16 cvt, in-register. av[c][r] = hT feature 16c+4q+r (col t).
    bf16x4 av[4];
#pragma unroll
    for (int c = 0; c < 4; c++) {
#pragma unroll
      for (int r = 0; r < 4; r++) {
        float v = hacc[c][r];
        v = fmaxf(v, 0.f) + fminf(__expf(v) - 1.f, 0.f);   // ELU
        av[c][r] = (__bf16)v;
      }
    }
    // K=32 B-frags for GEMM2: concat chunk pair (2e, 2e+1) per the feature(k) relabel.
    bf16x8 bfrag[2];
#pragma unroll
    for (int e = 0; e < 2; e++)
      bfrag[e] = __builtin_shufflevector(av[2 * e], av[2 * e + 1], 0, 1, 2, 3, 4, 5, 6, 7);

    // GEMM2 swapped: yT = W2^T @ hT, residual via identity-A MFMA, b2 via C.
#pragma unroll
    for (int c2 = 0; c2 < 2; c2++) {
      f32x4 acc = __builtin_amdgcn_mfma_f32_16x16x32_bf16(ifr[c2], afr[u], b2f2[c2], 0, 0, 0);
#pragma unroll
      for (int e = 0; e < 2; e++)
        acc = __builtin_amdgcn_mfma_f32_16x16x32_bf16(w2f[e * 2 + c2], bfrag[e], acc, 0, 0, 0);
#pragma unroll
      for (int r = 0; r < 4; r++) {
        int cc  = c2 * 16 + q * 4 + r;          // out col within block
        int idx = cc * 512 + t * 32 + n;        // [colblk][row][k=n]
        tile[swz(idx)] = f2b_hw(acc[r]);
      }
    }
  }
}

__global__ __launch_bounds__(256) void mixer_kernel(
    const float* __restrict__ x,
    const float* __restrict__ b1a, const float* __restrict__ b2a,
    const float* __restrict__ b1b, const float* __restrict__ b2b,
    const u16t* __restrict__ pW1, const u16t* __restrict__ pW2,
    float* __restrict__ out) {
  __shared__ u16t tile[16384];                  // 32 KB: [colblk 0..31][row 0..15][k 0..31]

  const int tid  = threadIdx.x;
  const int wave = tid >> 6, lane = tid & 63;
  const int q = lane >> 4, t = lane & 15;
  const int r0 = blockIdx.x * 16;
  const int n0 = wave * 8;

  // identity A-frags for the swapped residual MFMA: A[m=t][k=8q+j] = (8q+j == 16c2+t)
  bf16x8 ifr[2];
#pragma unroll
  for (int c2 = 0; c2 < 2; c2++) {
    union { u16t us[8]; bf16x8 v; } w;
#pragma unroll
    for (int j = 0; j < 8; j++)
      w.us[j] = ((q * 8 + j) == (c2 * 16 + t)) ? (u16t)0x3F80 : (u16t)0;
    ifr[c2] = w.v;
  }

  // ---- layer 1 input frags straight from global ----
  bf16x8 afr[8];
#pragma unroll
  for (int u = 0; u < 8; u++) {
    const float* gp = x + (size_t)(r0 + t) * 1024 + (n0 + u) * 32 + q * 8;
    float4 v0 = *(const float4*)gp;
    float4 v1 = *(const float4*)(gp + 4);
    union { __bf16 h[8]; bf16x8 v; } a;
    a.h[0] = (__bf16)v0.x; a.h[1] = (__bf16)v0.y; a.h[2] = (__bf16)v0.z; a.h[3] = (__bf16)v0.w;
    a.h[4] = (__bf16)v1.x; a.h[5] = (__bf16)v1.y; a.h[6] = (__bf16)v1.z; a.h[7] = (__bf16)v1.w;
    afr[u] = a.v;
  }

  compute_layer<0>(afr, tile, pW1, pW2, b1a, b2a, n0, lane, q, t, ifr);
  __syncthreads();

  // ---- layer 2 gather: z_n2[t][8q+j] = y1[t][(8q+j)*32 + n2] -> two ds_read_b64 per u ----
#pragma unroll
  for (int u = 0; u < 8; u++) {
    const int n2 = n0 + u;
    int idx = n2 * 512 + t * 32 + q * 8;
    union { ushort4 h[2]; bf16x8 v; } a;
    a.h[0] = *(const ushort4*)&tile[swz(idx)];
    a.h[1] = *(const ushort4*)&tile[swz(idx + 4)];
    afr[u] = a.v;
  }
  __syncthreads();                              // gathers done before tile is overwritten

  compute_layer<1>(afr, tile, pW1, pW2, b1b, b2b, n0, lane, q, t, ifr);
  __syncthreads();

  // ---- output: out[m][cc*32+n2] = y2[m][32*n2+cc]; tile layout makes this 4-contig ----
#pragma unroll
  for (int i = 0; i < 16; i++) {
    int c  = tid >> 3;
    int n2 = (tid & 7) * 4;
    int idx = c * 512 + i * 32 + n2;
    ushort4 hv = *(const ushort4*)&tile[swz(idx)];
    float4 o;
    o.x = b2f(hv.x); o.y = b2f(hv.y); o.z = b2f(hv.z); o.w = b2f(hv.w);
    *(float4*)(out + (size_t)(r0 + i) * 1024 + tid * 4) = o;
  }
}

extern "C" void kernel_launch(void* const* d_in, const int* in_sizes, int n_in,
                              void* d_out, int out_size, void* d_ws, size_t ws_size,
                              hipStream_t stream) {
  const float* x   = (const float*)d_in[0];
  const float* W1a = (const float*)d_in[1];
  const float* b1a = (const float*)d_in[2];
  const float* W2a = (const float*)d_in[3];
  const float* b2a = (const float*)d_in[4];
  const float* W1b = (const float*)d_in[5];
  const float* b1b = (const float*)d_in[6];
  const float* W2b = (const float*)d_in[7];
  const float* b2b = (const float*)d_in[8];
  float* out = (float*)d_out;

  u16t* pW1 = (u16t*)d_ws;
  u16t* pW2 = pW1 + 131072;   // 256 KB each, 512 KB total in d_ws

  const int rows = in_sizes[0] / 1024;

  pack_weights<<<128, 256, 0, stream>>>(W1a, W2a, W1b, W2b, pW1, pW2);
  mixer_kernel<<<rows / 16, 256, 0, stream>>>(x, b1a, b2a, b1b, b2b, pW1, pW2, out);
}

// Round 5
// 162.420 us; speedup vs baseline: 1.2247x; 1.1241x over previous
//
#include <hip/hip_runtime.h>

// BlockResMLP mixer, fused single kernel — swapped-MFMA, K=32-only, low-VGPR.
// 16384 rows x 1024 cols fp32. Two layers of per-block MLP(32->64 ELU ->32)+residual,
// 32x32 cross-block transpose between layers (gap=1 then gap=32).
//
// GEMM1 computed SWAPPED (hT = mfma(A=W1^T-frag, B=x^T-frag)) so each lane holds
// h[16c+4q+r][t]. GEMM2 (yT = W2^T @ hT) chains with ZERO data movement: the K=32
// B-fragment over chunk-pair e is the register CONCATENATION {av[2e], av[2e+1]}
// under feature(k=8q+j) = 32e + 16*(j>=4) + 4q + (j&3); the W2 pack permutes
// features identically. Biases fold into MFMA C. Inter-layer transpose via one
// 32KB tile [colblk][row][k] + XOR swizzle: vector ds_read_b64 gathers.
//
// Round-3 post-mortem: __launch_bounds__(256,4) -> 64-VGPR cap -> 80MB spill.
// Round-4 post-mortem: no hint -> 132 VGPR -> crosses the 128 HW occupancy step
// (waves/EU 4 -> 2, m69), latency-bound kernel slowed 61->85us. This version:
// minimal live set (chunk-paired GEMM1, loads at point of use) + (256,2) cap=128.

typedef unsigned short u16t;
typedef __bf16 bf16x8 __attribute__((ext_vector_type(8)));
typedef __bf16 bf16x4 __attribute__((ext_vector_type(4)));
typedef float f32x4 __attribute__((ext_vector_type(4)));

__device__ __forceinline__ u16t f2b(float f) {           // fp32 -> bf16 RNE (pack kernel)
  union { float f; unsigned u; } v; v.f = f;
  unsigned r = v.u + 0x7FFFu + ((v.u >> 16) & 1u);
  return (u16t)(r >> 16);
}
__device__ __forceinline__ float b2f(u16t h) {
  union { unsigned u; float f; } v; v.u = ((unsigned)h) << 16;
  return v.f;
}
__device__ __forceinline__ u16t f2b_hw(float f) {        // HW v_cvt (RNE) path
  union { __bf16 h; u16t u; } v; v.h = (__bf16)f;
  return v.u;
}
__device__ __forceinline__ float elu(float v) {
  return fmaxf(v, 0.f) + fminf(__expf(v) - 1.f, 0.f);
}

// Tile swizzle: XOR bits 2..5 with (bits 6..9 ^ bits 10..13). Keeps 8B groups
// contiguous+aligned (vector reads OK), spreads strided scalar stores across banks.
__device__ __forceinline__ int swz(int idx) {
  return idx ^ ((((idx >> 6) ^ (idx >> 10)) & 15) << 2);
}

// ---------------- weight pack: fp32 -> bf16 MFMA fragment order ----------------
// pW1[L][n][c][lane][j]  : W1[n][k=q*8+j][c*16+t]                       (A-frag, K=32)
// pW2[L][n][f][lane][j]  : f = e*2+c2;
//     j<4 : W2[n][32e      + 4q + j    ][16c2+t]
//     j>=4: W2[n][32e + 16 + 4q + (j-4)][16c2+t]                        (A-frag, K=32, paired chunks)
__global__ __launch_bounds__(256) void pack_weights(
    const float* __restrict__ W1a, const float* __restrict__ W2a,
    const float* __restrict__ W1b, const float* __restrict__ W2b,
    u16t* __restrict__ pW1, u16t* __restrict__ pW2) {
  int tidg = blockIdx.x * 256 + threadIdx.x;   // 0..32767
  int tensor = tidg >> 14;                     // 0 = W1, 1 = W2
  int r  = tidg & 16383;
  int L  = r >> 13;
  int r2 = r & 8191;
  int n    = r2 >> 8;
  int f    = (r2 >> 6) & 3;
  int lane = r2 & 63;
  int q = lane >> 4, t = lane & 15;

  union { u16t us[8]; uint4 v; } w;
  if (tensor == 0) {
    const float* src = L ? W1b : W1a;
#pragma unroll
    for (int j = 0; j < 8; j++)
      w.us[j] = f2b(src[n * 2048 + (q * 8 + j) * 64 + f * 16 + t]);
    *(uint4*)(pW1 + (size_t)((((L * 32 + n) * 4 + f) * 64 + lane) * 8)) = w.v;
  } else {
    const float* src = L ? W2b : W2a;
    int e = f >> 1, c2 = f & 1;
#pragma unroll
    for (int j = 0; j < 8; j++) {
      int feat = 32 * e + (j >= 4 ? 16 : 0) + 4 * q + (j & 3);
      w.us[j] = f2b(src[n * 2048 + feat * 32 + 16 * c2 + t]);
    }
    *(uint4*)(pW2 + (size_t)((((L * 32 + n) * 4 + f) * 64 + lane) * 8)) = w.v;
  }
}

// ---------------- per-layer compute (8 blocks per wave) ----------------
// afr[u]: x-frag, lane (q,t) holds x[t][8q+j] of block n0+u.
// Writes y[t][32n + cc] (cc = 16c2+4q+r) to tile at logical idx = cc*512 + t*32 + n.
template <int L>
__device__ __forceinline__ void compute_layer(
    const bf16x8* __restrict__ afr, u16t* __restrict__ tile,
    const u16t* __restrict__ pW1, const u16t* __restrict__ pW2,
    const float* __restrict__ b1, const float* __restrict__ b2,
    int n0, int lane, int q, int t, const bf16x8* __restrict__ ifr) {
#pragma unroll
  for (int u = 0; u < 8; u++) {
    const int n = n0 + u;
    const int wbase = ((L * 32 + n) * 4) * 512 + lane * 8;

    // GEMM1 swapped, chunk-PAIRED to minimize live registers: only one pair's
    // hacc (8 regs) + w1 frags (8 regs) live at a time; result collapses to the
    // bf16 bfrag immediately.
    bf16x8 bfrag[2];
#pragma unroll
    for (int e = 0; e < 2; e++) {
      bf16x8 w1lo = *(const bf16x8*)(pW1 + wbase + (2 * e) * 512);
      bf16x8 w1hi = *(const bf16x8*)(pW1 + wbase + (2 * e + 1) * 512);
      f32x4 b1lo = *(const f32x4*)(b1 + n * 64 + (2 * e) * 16 + q * 4);
      f32x4 b1hi = *(const f32x4*)(b1 + n * 64 + (2 * e + 1) * 16 + q * 4);
      f32x4 h0 = __builtin_amdgcn_mfma_f32_16x16x32_bf16(w1lo, afr[u], b1lo, 0, 0, 0);
      f32x4 h1 = __builtin_amdgcn_mfma_f32_16x16x32_bf16(w1hi, afr[u], b1hi, 0, 0, 0);
      bf16x4 a0, a1;
#pragma unroll
      for (int r = 0; r < 4; r++) {
        a0[r] = (__bf16)elu(h0[r]);
        a1[r] = (__bf16)elu(h1[r]);
      }
      bfrag[e] = __builtin_shufflevector(a0, a1, 0, 1, 2, 3, 4, 5, 6, 7);
    }

    // GEMM2 swapped: yT = W2^T @ hT; residual via identity-A MFMA; b2 via C.
    // W2 frags and b2 loaded at point of use (compiler hoists up to the reg cap).
#pragma unroll
    for (int c2 = 0; c2 < 2; c2++) {
      f32x4 b2v = *(const f32x4*)(b2 + n * 32 + c2 * 16 + q * 4);
      f32x4 acc = __builtin_amdgcn_mfma_f32_16x16x32_bf16(ifr[c2], afr[u], b2v, 0, 0, 0);
#pragma unroll
      for (int e = 0; e < 2; e++) {
        bf16x8 w2f = *(const bf16x8*)(pW2 + wbase + (e * 2 + c2) * 512);
        acc = __builtin_amdgcn_mfma_f32_16x16x32_bf16(w2f, bfrag[e], acc, 0, 0, 0);
      }
#pragma unroll
      for (int r = 0; r < 4; r++) {
        int cc  = c2 * 16 + q * 4 + r;          // out col within block
        int idx = cc * 512 + t * 32 + n;        // [colblk][row][k=n]
        tile[swz(idx)] = f2b_hw(acc[r]);
      }
    }
  }
}

__global__ __launch_bounds__(256, 2) void mixer_kernel(
    const float* __restrict__ x,
    const float* __restrict__ b1a, const float* __restrict__ b2a,
    const float* __restrict__ b1b, const float* __restrict__ b2b,
    const u16t* __restrict__ pW1, const u16t* __restrict__ pW2,
    float* __restrict__ out) {
  __shared__ u16t tile[16384];                  // 32 KB: [colblk 0..31][row 0..15][k 0..31]

  const int tid  = threadIdx.x;
  const int wave = tid >> 6, lane = tid & 63;
  const int q = lane >> 4, t = lane & 15;
  const int r0 = blockIdx.x * 16;
  const int n0 = wave * 8;

  // identity A-frags for the swapped residual MFMA: A[m=t][k=8q+j] = (8q+j == 16c2+t)
  bf16x8 ifr[2];
#pragma unroll
  for (int c2 = 0; c2 < 2; c2++) {
    union { u16t us[8]; bf16x8 v; } w;
#pragma unroll
    for (int j = 0; j < 8; j++)
      w.us[j] = ((q * 8 + j) == (c2 * 16 + t)) ? (u16t)0x3F80 : (u16t)0;
    ifr[c2] = w.v;
  }

  // ---- layer 1 input frags straight from global ----
  bf16x8 afr[8];
#pragma unroll
  for (int u = 0; u < 8; u++) {
    const float* gp = x + (size_t)(r0 + t) * 1024 + (n0 + u) * 32 + q * 8;
    float4 v0 = *(const float4*)gp;
    float4 v1 = *(const float4*)(gp + 4);
    union { __bf16 h[8]; bf16x8 v; } a;
    a.h[0] = (__bf16)v0.x; a.h[1] = (__bf16)v0.y; a.h[2] = (__bf16)v0.z; a.h[3] = (__bf16)v0.w;
    a.h[4] = (__bf16)v1.x; a.h[5] = (__bf16)v1.y; a.h[6] = (__bf16)v1.z; a.h[7] = (__bf16)v1.w;
    afr[u] = a.v;
  }

  compute_layer<0>(afr, tile, pW1, pW2, b1a, b2a, n0, lane, q, t, ifr);
  __syncthreads();

  // ---- layer 2 gather: z_n2[t][8q+j] = y1[t][(8q+j)*32 + n2] -> two ds_read_b64 per u ----
#pragma unroll
  for (int u = 0; u < 8; u++) {
    const int n2 = n0 + u;
    int idx = n2 * 512 + t * 32 + q * 8;
    union { ushort4 h[2]; bf16x8 v; } a;
    a.h[0] = *(const ushort4*)&tile[swz(idx)];
    a.h[1] = *(const ushort4*)&tile[swz(idx + 4)];
    afr[u] = a.v;
  }
  __syncthreads();                              // gathers done before tile is overwritten

  compute_layer<1>(afr, tile, pW1, pW2, b1b, b2b, n0, lane, q, t, ifr);
  __syncthreads();

  // ---- output: out[m][cc*32+n2] = y2[m][32*n2+cc]; tile layout makes this 4-contig ----
#pragma unroll
  for (int i = 0; i < 16; i++) {
    int c  = tid >> 3;
    int n2 = (tid & 7) * 4;
    int idx = c * 512 + i * 32 + n2;
    ushort4 hv = *(const ushort4*)&tile[swz(idx)];
    float4 o;
    o.x = b2f(hv.x); o.y = b2f(hv.y); o.z = b2f(hv.z); o.w = b2f(hv.w);
    *(float4*)(out + (size_t)(r0 + i) * 1024 + tid * 4) = o;
  }
}

extern "C" void kernel_launch(void* const* d_in, const int* in_sizes, int n_in,
                              void* d_out, int out_size, void* d_ws, size_t ws_size,
                              hipStream_t stream) {
  const float* x   = (const float*)d_in[0];
  const float* W1a = (const float*)d_in[1];
  const float* b1a = (const float*)d_in[2];
  const float* W2a = (const float*)d_in[3];
  const float* b2a = (const float*)d_in[4];
  const float* W1b = (const float*)d_in[5];
  const float* b1b = (const float*)d_in[6];
  const float* W2b = (const float*)d_in[7];
  const float* b2b = (const float*)d_in[8];
  float* out = (float*)d_out;

  u16t* pW1 = (u16t*)d_ws;
  u16t* pW2 = pW1 + 131072;   // 256 KB each, 512 KB total in d_ws

  const int rows = in_sizes[0] / 1024;

  pack_weights<<<128, 256, 0, stream>>>(W1a, W2a, W1b, W2b, pW1, pW2);
  mixer_kernel<<<rows / 16, 256, 0, stream>>>(x, b1a, b2a, b1b, b2b, pW1, pW2, out);
}